// Round 8
// baseline (299.638 us; speedup 1.0000x reference)
//
#include <hip/hip_runtime.h>

#define BB 4
#define NN 512
#define DD 16
#define EE 16
#define HH 128
#define NPH 4   // j-phases per block

#define LD4(p) (*(const float4*)(p))

// One fused kernel: block per (b,i), 128 threads (t&31 -> h-quad, t>>5 -> j-phase).
// proj_j is RECOMPUTED inline from node_feature (no pj table, no cache-resident
// re-read set) so plain write-back stores have no pollution victim.
__global__ __launch_bounds__(128, 2)
void fused_kernel(const float* __restrict__ node_feature,
                  const float* __restrict__ adjacency,
                  const float* __restrict__ edge_feature,
                  const float* __restrict__ W_edge,
                  const float* __restrict__ b_edge,
                  const float* __restrict__ W_feat,
                  const float* __restrict__ b_feat,
                  float* __restrict__ out_end,
                  float* __restrict__ out_edge) {
    const int bi = blockIdx.x;           // b*N + i
    const int b  = bi >> 9;
    const int t  = threadIdx.x;          // 0..127
    const int hq = t & 31;
    const int jl = t >> 5;               // 0..3
    const int h0 = hq * 4;

    // Weight columns for this thread's 4 h's (compiler may keep in VGPRs or
    // re-load from L1 -- proven perf-neutral in rounds 2/6)
    float4 we[EE];
#pragma unroll
    for (int e = 0; e < EE; ++e)
        we[e] = LD4(W_edge + (2 * DD + e) * HH + h0);
    float4 wj[DD];
#pragma unroll
    for (int d = 0; d < DD; ++d)
        wj[d] = LD4(W_edge + (DD + d) * HH + h0);

    // pi = b_edge + nf_i @ Wi   (own row i)
    float4 pi = LD4(b_edge + h0);
    {
        const float* nfi = node_feature + bi * DD;
#pragma unroll
        for (int d4 = 0; d4 < DD; d4 += 4) {
            float4 v = LD4(nfi + d4);
            float nd[4] = {v.x, v.y, v.z, v.w};
#pragma unroll
            for (int q = 0; q < 4; ++q) {
                float4 wi = LD4(W_edge + (d4 + q) * HH + h0);
                pi.x = fmaf(nd[q], wi.x, pi.x);
                pi.y = fmaf(nd[q], wi.y, pi.y);
                pi.z = fmaf(nd[q], wi.z, pi.z);
                pi.w = fmaf(nd[q], wi.w, pi.w);
            }
        }
    }

    const float* efb  = edge_feature + (size_t)bi * NN * EE;
    const float* adjr = adjacency + (size_t)bi * NN;
    const float* nfb  = node_feature + (b * NN) * DD;
    float*       eob  = out_edge + (size_t)bi * NN * HH;

    float4 msg = make_float4(0.f, 0.f, 0.f, 0.f);

    int j = jl;
    // prefetch iteration 0 (ef + adj; nfj loaded direct, it's L2-resident)
    float4 efA0 = LD4(efb + j * EE + 0);
    float4 efA1 = LD4(efb + j * EE + 4);
    float4 efA2 = LD4(efb + j * EE + 8);
    float4 efA3 = LD4(efb + j * EE + 12);
    float  adjA = adjr[j];

    for (int it = 0; it < NN / NPH; ++it) {
        const int jn = j + NPH;
        const int jc = (jn < NN) ? jn : j;   // clamp prefetch addr (last iter)

        // ---- prefetch next iteration ----
        float4 efB0 = LD4(efb + jc * EE + 0);
        float4 efB1 = LD4(efb + jc * EE + 4);
        float4 efB2 = LD4(efb + jc * EE + 8);
        float4 efB3 = LD4(efb + jc * EE + 12);
        float  adjB = adjr[jc];

        // ---- compute current: acc = pi + nf_j @ Wj + ef @ We ----
        float4 acc = pi;
        {
            const float* nfj = nfb + j * DD;
#pragma unroll
            for (int d4 = 0; d4 < DD; d4 += 4) {
                float4 v = LD4(nfj + d4);
                float nd[4] = {v.x, v.y, v.z, v.w};
#pragma unroll
                for (int q = 0; q < 4; ++q) {
                    acc.x = fmaf(nd[q], wj[d4 + q].x, acc.x);
                    acc.y = fmaf(nd[q], wj[d4 + q].y, acc.y);
                    acc.z = fmaf(nd[q], wj[d4 + q].z, acc.z);
                    acc.w = fmaf(nd[q], wj[d4 + q].w, acc.w);
                }
            }
        }

#define EFMA(v, e0) \
        acc.x = fmaf((v).x, we[e0+0].x, acc.x); acc.y = fmaf((v).x, we[e0+0].y, acc.y); \
        acc.z = fmaf((v).x, we[e0+0].z, acc.z); acc.w = fmaf((v).x, we[e0+0].w, acc.w); \
        acc.x = fmaf((v).y, we[e0+1].x, acc.x); acc.y = fmaf((v).y, we[e0+1].y, acc.y); \
        acc.z = fmaf((v).y, we[e0+1].z, acc.z); acc.w = fmaf((v).y, we[e0+1].w, acc.w); \
        acc.x = fmaf((v).z, we[e0+2].x, acc.x); acc.y = fmaf((v).z, we[e0+2].y, acc.y); \
        acc.z = fmaf((v).z, we[e0+2].z, acc.z); acc.w = fmaf((v).z, we[e0+2].w, acc.w); \
        acc.x = fmaf((v).w, we[e0+3].x, acc.x); acc.y = fmaf((v).w, we[e0+3].y, acc.y); \
        acc.z = fmaf((v).w, we[e0+3].z, acc.z); acc.w = fmaf((v).w, we[e0+3].w, acc.w);

        EFMA(efA0, 0)
        EFMA(efA1, 4)
        EFMA(efA2, 8)
        EFMA(efA3, 12)
#undef EFMA

        acc.x = fmaxf(acc.x, 0.f);
        acc.y = fmaxf(acc.y, 0.f);
        acc.z = fmaxf(acc.z, 0.f);
        acc.w = fmaxf(acc.w, 0.f);

        // PLAIN write-back store: no cache-resident re-read set exists to
        // pollute (pj eliminated), and write-back drains at ~6.7 TB/s.
        *(float4*)(eob + (size_t)j * HH + h0) = acc;

        msg.x = fmaf(adjA, acc.x, msg.x);
        msg.y = fmaf(adjA, acc.y, msg.y);
        msg.z = fmaf(adjA, acc.z, msg.z);
        msg.w = fmaf(adjA, acc.w, msg.w);

        // rotate prefetch buffers
        efA0 = efB0; efA1 = efB1; efA2 = efB2; efA3 = efB3;
        adjA = adjB;
        j = jn;
    }

    // Reduce message across the 4 j-phases, then ending = relu([msg,nf] @ W_feat + b_feat)
    __shared__ float msgred[NPH][HH];
    *(float4*)&msgred[jl][h0] = msg;
    __syncthreads();

    if (jl == 0) {
        float4 acc = LD4(b_feat + h0);
#pragma unroll 4
        for (int k = 0; k < HH; ++k) {
            float m = msgred[0][k] + msgred[1][k] + msgred[2][k] + msgred[3][k];
            float4 w = LD4(W_feat + k * HH + h0);
            acc.x = fmaf(m, w.x, acc.x);
            acc.y = fmaf(m, w.y, acc.y);
            acc.z = fmaf(m, w.z, acc.z);
            acc.w = fmaf(m, w.w, acc.w);
        }
        const float* nfi = node_feature + bi * DD;
#pragma unroll
        for (int d = 0; d < DD; ++d) {
            float m = nfi[d];
            float4 w = LD4(W_feat + (HH + d) * HH + h0);
            acc.x = fmaf(m, w.x, acc.x);
            acc.y = fmaf(m, w.y, acc.y);
            acc.z = fmaf(m, w.z, acc.z);
            acc.w = fmaf(m, w.w, acc.w);
        }
        acc.x = fmaxf(acc.x, 0.f);
        acc.y = fmaxf(acc.y, 0.f);
        acc.z = fmaxf(acc.z, 0.f);
        acc.w = fmaxf(acc.w, 0.f);
        *(float4*)(out_end + bi * HH + h0) = acc;
    }
}

extern "C" void kernel_launch(void* const* d_in, const int* in_sizes, int n_in,
                              void* d_out, int out_size, void* d_ws, size_t ws_size,
                              hipStream_t stream) {
    const float* node_feature = (const float*)d_in[0];
    const float* adjacency    = (const float*)d_in[1];
    const float* edge_feature = (const float*)d_in[2];
    // d_in[3] = node_mask (unused by reference math)
    const float* W_edge = (const float*)d_in[4];
    const float* b_edge = (const float*)d_in[5];
    const float* W_feat = (const float*)d_in[6];
    const float* b_feat = (const float*)d_in[7];

    float* out_end  = (float*)d_out;                       // (B,N,H) first
    float* out_edge = out_end + (size_t)BB * NN * HH;      // then (B,N,N,H)

    fused_kernel<<<BB * NN, 128, 0, stream>>>(
        node_feature, adjacency, edge_feature, W_edge, b_edge,
        W_feat, b_feat, out_end, out_edge);
}

// Round 9
// 139.493 us; speedup vs baseline: 2.1480x; 2.1480x over previous
//
#include <hip/hip_runtime.h>

#define BB 4
#define NN 512
#define DD 16
#define EE 16
#define HH 128

typedef float f32x4 __attribute__((ext_vector_type(4)));

#define LD4(p) (*(const float4*)(p))

// Kernel 1: proj_j[b,j,h] = sum_d node_feature[b,j,d] * W_edge[D+d][h]
__global__ void proj_j_kernel(const float* __restrict__ nf,
                              const float* __restrict__ W_edge,
                              float* __restrict__ pj) {
    int idx = blockIdx.x * 256 + threadIdx.x;
    if (idx >= BB * NN * HH) return;
    int h  = idx & (HH - 1);
    int bj = idx >> 7;
    const float* row = nf + bj * DD;
    float acc = 0.f;
#pragma unroll
    for (int d = 0; d < DD; ++d)
        acc = fmaf(row[d], W_edge[(DD + d) * HH + h], acc);
    pj[idx] = acc;
}

// Kernel 2: one block per (b,i). 128 threads = 2 waves.
// Wave w handles rows {4*it + 2w, 4*it + 2w + 1}; lanes 0-31 take the even
// row, lanes 32-63 the odd row (hi). edge_feature + adjacency are loaded via
// WAVE-UNIFORM addresses (readfirstlane) -> scalar s_load path (lgkmcnt),
// freeing the vector vmcnt queue for {pj load, NT store} only.
template <bool USE_WS>
__global__ __launch_bounds__(128, 2)
void fused_kernel(const float* __restrict__ node_feature,
                  const float* __restrict__ adjacency,
                  const float* __restrict__ edge_feature,
                  const float* __restrict__ W_edge,
                  const float* __restrict__ b_edge,
                  const float* __restrict__ W_feat,
                  const float* __restrict__ b_feat,
                  const float* __restrict__ pj,
                  float* __restrict__ out_end,
                  float* __restrict__ out_edge) {
    const int bi = blockIdx.x;           // b*N + i
    const int b  = bi >> 9;
    const int t  = threadIdx.x;          // 0..127
    const int hq = t & 31;
    const int h0 = hq * 4;
    const bool hi = (t & 32) != 0;       // odd row within the wave's pair
    const int jw = __builtin_amdgcn_readfirstlane(2 * (t >> 6)); // 0 or 2 (SGPR)

    // We columns (rows 2D..2D+E-1 of W_edge)
    float4 we[EE];
#pragma unroll
    for (int e = 0; e < EE; ++e)
        we[e] = LD4(W_edge + (2 * DD + e) * HH + h0);

    // pi = b_edge + nf_i @ Wi   (own row i)
    float4 pi = LD4(b_edge + h0);
    {
        const float* nfi = node_feature + bi * DD;
#pragma unroll
        for (int d4 = 0; d4 < DD; d4 += 4) {
            float4 v = LD4(nfi + d4);
            float nd[4] = {v.x, v.y, v.z, v.w};
#pragma unroll
            for (int q = 0; q < 4; ++q) {
                float4 wi = LD4(W_edge + (d4 + q) * HH + h0);
                pi.x = fmaf(nd[q], wi.x, pi.x);
                pi.y = fmaf(nd[q], wi.y, pi.y);
                pi.z = fmaf(nd[q], wi.z, pi.z);
                pi.w = fmaf(nd[q], wi.w, pi.w);
            }
        }
    }

    const float* efb  = edge_feature + (size_t)bi * NN * EE;
    const float* adjr = adjacency + (size_t)bi * NN;
    const float* pjb  = pj + (b * NN) * HH;
    float*       eob  = out_edge + (size_t)bi * NN * HH;

    float4 msg = make_float4(0.f, 0.f, 0.f, 0.f);

    // ---- prefetch iteration 0 ----
    int j0 = jw;                                   // uniform row base
    float sefA0[EE], sefA1[EE];
#pragma unroll
    for (int e = 0; e < EE; ++e) {
        sefA0[e] = efb[j0 * EE + e];               // uniform addr -> s_load
        sefA1[e] = efb[(j0 + 1) * EE + e];
    }
    float adjA0 = adjr[j0];
    float adjA1 = adjr[j0 + 1];
    int   jsel  = j0 + (hi ? 1 : 0);               // per-lane row
    float4 pjA  = make_float4(0.f, 0.f, 0.f, 0.f);
    if constexpr (USE_WS) pjA = LD4(pjb + jsel * HH + h0);

    for (int it = 0; it < NN / 4; ++it) {
        const int itn = (it + 1 < NN / 4) ? it + 1 : it;
        const int j0n = 4 * itn + jw;              // uniform next base
        const int jseln = j0n + (hi ? 1 : 0);

        // ---- prefetch next iteration (scalar ef/adj, vector pj) ----
        float sefB0[EE], sefB1[EE];
#pragma unroll
        for (int e = 0; e < EE; ++e) {
            sefB0[e] = efb[j0n * EE + e];
            sefB1[e] = efb[(j0n + 1) * EE + e];
        }
        float adjB0 = adjr[j0n];
        float adjB1 = adjr[j0n + 1];
        float4 pjB  = make_float4(0.f, 0.f, 0.f, 0.f);
        if constexpr (USE_WS) pjB = LD4(pjb + jseln * HH + h0);

        // ---- compute current ----
        float4 acc;
        if constexpr (USE_WS) {
            acc.x = pi.x + pjA.x;
            acc.y = pi.y + pjA.y;
            acc.z = pi.z + pjA.z;
            acc.w = pi.w + pjA.w;
        } else {
            acc = pi;
        }

        float ef_[EE];
#pragma unroll
        for (int e = 0; e < EE; ++e)
            ef_[e] = hi ? sefA1[e] : sefA0[e];     // 1 cndmask each

#pragma unroll
        for (int e = 0; e < EE; ++e) {
            acc.x = fmaf(ef_[e], we[e].x, acc.x);
            acc.y = fmaf(ef_[e], we[e].y, acc.y);
            acc.z = fmaf(ef_[e], we[e].z, acc.z);
            acc.w = fmaf(ef_[e], we[e].w, acc.w);
        }
        acc.x = fmaxf(acc.x, 0.f);
        acc.y = fmaxf(acc.y, 0.f);
        acc.z = fmaxf(acc.z, 0.f);
        acc.w = fmaxf(acc.w, 0.f);

        // nontemporal store: don't write-allocate 537MB into L2/L3
        __builtin_nontemporal_store((f32x4){acc.x, acc.y, acc.z, acc.w},
                                    (f32x4*)(eob + (size_t)jsel * HH + h0));

        float adjv = hi ? adjA1 : adjA0;
        msg.x = fmaf(adjv, acc.x, msg.x);
        msg.y = fmaf(adjv, acc.y, msg.y);
        msg.z = fmaf(adjv, acc.z, msg.z);
        msg.w = fmaf(adjv, acc.w, msg.w);

        // rotate prefetch buffers
#pragma unroll
        for (int e = 0; e < EE; ++e) { sefA0[e] = sefB0[e]; sefA1[e] = sefB1[e]; }
        adjA0 = adjB0; adjA1 = adjB1; pjA = pjB;
        jsel = jseln;
    }

    // Reduce message across the 4 row-phases, then ending = relu([msg,nf]@W_feat + b_feat)
    __shared__ float msgred[4][HH];
    *(float4*)&msgred[t >> 5][h0] = msg;
    __syncthreads();

    if (t < 32) {
        float4 acc = LD4(b_feat + h0);
#pragma unroll 4
        for (int k = 0; k < HH; ++k) {
            float m = msgred[0][k] + msgred[1][k] + msgred[2][k] + msgred[3][k];
            float4 w = LD4(W_feat + k * HH + h0);
            acc.x = fmaf(m, w.x, acc.x);
            acc.y = fmaf(m, w.y, acc.y);
            acc.z = fmaf(m, w.z, acc.z);
            acc.w = fmaf(m, w.w, acc.w);
        }
        const float* nfi = node_feature + bi * DD;
#pragma unroll
        for (int d = 0; d < DD; ++d) {
            float m = nfi[d];
            float4 w = LD4(W_feat + (HH + d) * HH + h0);
            acc.x = fmaf(m, w.x, acc.x);
            acc.y = fmaf(m, w.y, acc.y);
            acc.z = fmaf(m, w.z, acc.z);
            acc.w = fmaf(m, w.w, acc.w);
        }
        acc.x = fmaxf(acc.x, 0.f);
        acc.y = fmaxf(acc.y, 0.f);
        acc.z = fmaxf(acc.z, 0.f);
        acc.w = fmaxf(acc.w, 0.f);
        *(float4*)(out_end + bi * HH + h0) = acc;
    }
}

extern "C" void kernel_launch(void* const* d_in, const int* in_sizes, int n_in,
                              void* d_out, int out_size, void* d_ws, size_t ws_size,
                              hipStream_t stream) {
    const float* node_feature = (const float*)d_in[0];
    const float* adjacency    = (const float*)d_in[1];
    const float* edge_feature = (const float*)d_in[2];
    // d_in[3] = node_mask (unused by reference math)
    const float* W_edge = (const float*)d_in[4];
    const float* b_edge = (const float*)d_in[5];
    const float* W_feat = (const float*)d_in[6];
    const float* b_feat = (const float*)d_in[7];

    float* out_end  = (float*)d_out;                       // (B,N,H) first
    float* out_edge = out_end + (size_t)BB * NN * HH;      // then (B,N,N,H)

    const size_t pj_bytes = (size_t)BB * NN * HH * sizeof(float);
    if (ws_size >= pj_bytes) {
        float* pj = (float*)d_ws;
        proj_j_kernel<<<(BB * NN * HH + 255) / 256, 256, 0, stream>>>(
            node_feature, W_edge, pj);
        fused_kernel<true><<<BB * NN, 128, 0, stream>>>(
            node_feature, adjacency, edge_feature, W_edge, b_edge,
            W_feat, b_feat, pj, out_end, out_edge);
    } else {
        fused_kernel<false><<<BB * NN, 128, 0, stream>>>(
            node_feature, adjacency, edge_feature, W_edge, b_edge,
            W_feat, b_feat, nullptr, out_end, out_edge);
    }
}